// Round 5
// baseline (182.122 us; speedup 1.0000x reference)
//
#include <hip/hip_runtime.h>

typedef unsigned short ushort;
typedef __attribute__((ext_vector_type(4)))  float  f32x4;
typedef __attribute__((ext_vector_type(16))) float  f32x16;
typedef __attribute__((ext_vector_type(8)))  short  s16x8;
typedef __attribute__((ext_vector_type(4)))  ushort u16x4;
typedef __attribute__((ext_vector_type(4)))  unsigned u32x4;

#define MFMA16(a, b, c) __builtin_amdgcn_mfma_f32_16x16x32_bf16((a), (b), (c), 0, 0, 0)
#define MFMA32(a, b, c) __builtin_amdgcn_mfma_f32_32x32x16_bf16((a), (b), (c), 0, 0, 0)

__device__ __forceinline__ ushort f2bf(float f) {
    unsigned u = __builtin_bit_cast(unsigned, f);
    u = (u + 0x7FFF + ((u >> 16) & 1)) >> 16;   // RNE
    return (ushort)u;
}

__device__ __forceinline__ unsigned cvtpk_bf16(float lo, float hi) {
    unsigned r;
    asm("v_cvt_pk_bf16_f32 %0, %1, %2" : "=v"(r) : "v"(lo), "v"(hi));
    return r;
}
// After the swap: a = [a_lo31 | b_lo31], b = [a_hi31 | b_hi31].
// Only safe when a and b are DISTINCT SSA values (regalloc coalescing hazard).
__device__ __forceinline__ void plswap(unsigned& a, unsigned& b) {
    asm volatile("v_permlane32_swap_b32 %0, %1" : "+v"(a), "+v"(b));
}
// Pair (lane ^ 32) reductions via verified __shfl_xor primitive.
__device__ __forceinline__ float pairmax(float x) {
    return fmaxf(x, __shfl_xor(x, 32));
}
__device__ __forceinline__ float pairsum(float x) {
    return x + __shfl_xor(x, 32);
}
// Raw 2^x (quarter-rate transcendental). exp() folded to exp2 via Q pre-scale.
__device__ __forceinline__ float fast_exp2(float x) {
    float r;
    asm("v_exp_f32 %0, %1" : "=v"(r) : "v"(x));
    return r;
}

__device__ __forceinline__ void gload_lds16(const ushort* g, ushort* l) {
    __builtin_amdgcn_global_load_lds(
        (const __attribute__((address_space(1))) void*)g,
        (__attribute__((address_space(3))) void*)l, 16, 0, 0);
}

// ---------------------------------------------------------------------------
// fp32 -> bf16 conversion (grid-stride, float4 in / 8B out)
// ---------------------------------------------------------------------------
__global__ __launch_bounds__(256) void cvt_f32_bf16(
    const float* __restrict__ in, ushort* __restrict__ out, int n4)
{
    int i = blockIdx.x * blockDim.x + threadIdx.x;
    const int stride = gridDim.x * blockDim.x;
    for (; i < n4; i += stride) {
        const float4 v = ((const float4*)in)[i];
        u16x4 o;
        o[0] = f2bf(v.x); o[1] = f2bf(v.y); o[2] = f2bf(v.z); o[3] = f2bf(v.w);
        ((u16x4*)out)[i] = o;
    }
}

// ---------------------------------------------------------------------------
// 128x128 tile GEMM mainloop (m97 structure), unchanged.
// ---------------------------------------------------------------------------
__device__ __forceinline__ void gemm128_mainloop(
    const ushort* __restrict__ A, const ushort* __restrict__ B, int K,
    int row0, int col0, ushort* As, ushort* Bs, f32x4 acc[4][4])
{
    const int t  = threadIdx.x;
    const int l  = t & 63;
    const int w  = t >> 6;
    const int lr = l & 15, lg = l >> 4;
    const int wm = w >> 1, wn = w & 1;

#pragma unroll
    for (int m = 0; m < 4; m++)
#pragma unroll
        for (int n = 0; n < 4; n++) acc[m][n] = (f32x4){0.f, 0.f, 0.f, 0.f};

    const ushort* ga0 = A + (row0 + (t >> 2)) * K + (t & 3) * 8;
    const ushort* gb0 = B + (col0 + (t >> 2)) * K + (t & 3) * 8;
    ushort* la0 = As + t * 8;
    ushort* lb0 = Bs + t * 8;
    const int rowsz = 64 * K;

    for (int k0 = 0; k0 < K; k0 += 32) {
        gload_lds16(ga0 + k0,          la0);
        gload_lds16(ga0 + rowsz + k0,  la0 + 2048);
        gload_lds16(gb0 + k0,          lb0);
        gload_lds16(gb0 + rowsz + k0,  lb0 + 2048);
        __syncthreads();

        s16x8 af[4], bfr[4];
#pragma unroll
        for (int m = 0; m < 4; m++)
            af[m] = *(const s16x8*)&As[(wm * 64 + m * 16 + lr) * 32 + lg * 8];
#pragma unroll
        for (int n = 0; n < 4; n++)
            bfr[n] = *(const s16x8*)&Bs[(wn * 64 + n * 16 + lr) * 32 + lg * 8];
#pragma unroll
        for (int m = 0; m < 4; m++)
#pragma unroll
            for (int n = 0; n < 4; n++)
                acc[m][n] = MFMA16(af[m], bfr[n], acc[m][n]);
        __syncthreads();
    }
}

// ---------------------------------------------------------------------------
// Kernel 1: QKV = x @ qkv_w^T, scatter into q[bh][n][64] (pre-scaled by
// SCALE*log2e so softmax uses exp2), k[bh][n][64], vT[bh][64][n].
// grid (64, 18), block 256.
// ---------------------------------------------------------------------------
__global__ __launch_bounds__(256) void qkv_gemm(
    const ushort* __restrict__ X, const ushort* __restrict__ W,
    ushort* __restrict__ qb, ushort* __restrict__ kb, ushort* __restrict__ vb)
{
    __shared__ __align__(16) ushort As[128 * 32];
    __shared__ __align__(16) ushort Bs[128 * 32];
    f32x4 acc[4][4];
    const int br = blockIdx.x, bc = blockIdx.y;
    gemm128_mainloop(X, W, 768, br * 128, bc * 128, As, Bs, acc);

    const int t = threadIdx.x, l = t & 63, w = t >> 6;
    const int lr = l & 15, lg = l >> 4, wm = w >> 1, wn = w & 1;
    const int p = (bc * 128) / 768;
    const int mrow0 = br * 128 + wm * 64 + lg * 4;
    const int ecolB = bc * 128 + wn * 64 + lr;
    const float QSCALE = 0.125f * 1.44269504088896f;  // SCALE * log2(e)

#pragma unroll
    for (int n = 0; n < 4; n++) {
        const int e   = ecolB + n * 16;
        const int rem = e - p * 768;
        const int h   = rem >> 6;
        const int hd  = rem & 63;
#pragma unroll
        for (int m = 0; m < 4; m++) {
            const int mr = mrow0 + m * 16;
            const int b  = mr >> 10;
            const int nn = mr & 1023;
            const f32x4 v = acc[m][n];
            const int bh = b * 12 + h;
            if (p == 0) {
                ushort* dst = qb + (bh * 1024 + nn) * 64 + hd;
#pragma unroll
                for (int r = 0; r < 4; r++) dst[r * 64] = f2bf(v[r] * QSCALE);
            } else if (p == 1) {
                ushort* dst = kb + (bh * 1024 + nn) * 64 + hd;
#pragma unroll
                for (int r = 0; r < 4; r++) dst[r * 64] = f2bf(v[r]);
            } else {
                u16x4 pk;
                pk[0] = f2bf(v[0]); pk[1] = f2bf(v[1]);
                pk[2] = f2bf(v[2]); pk[3] = f2bf(v[3]);
                *(u16x4*)(vb + (bh * 64 + hd) * 1024 + nn) = pk;
            }
        }
    }
}

// ---------------------------------------------------------------------------
// Kernel 2: flash attention, 32x32 swapped-QK, zero LDS, KVBLK=64 (two
// independent 32-kv sub-tiles per iteration sharing one softmax pass).
// grid (8 q-tiles of 128, 96 bh), block 256 = 4 waves; each wave owns 32 q.
// ---------------------------------------------------------------------------
__global__ __launch_bounds__(256) void attn_kernel(
    const ushort* __restrict__ qb, const ushort* __restrict__ kb,
    const ushort* __restrict__ vb, ushort* __restrict__ ao)
{
    const int qt = blockIdx.x, bh = blockIdx.y;
    const int b = bh / 12, h = bh - b * 12;
    const int t = threadIdx.x, l = t & 63, w = t >> 6;
    const int lq = l & 31, hi = l >> 5;
    const int qr0 = qt * 128 + w * 32;

    // Q fragments: B-operand, col=q=lq, k=d-slice s*16 + hi*8
    const ushort* qlane = qb + (bh * 1024 + qr0 + lq) * 64 + hi * 8;
    s16x8 qf[4];
#pragma unroll
    for (int s = 0; s < 4; s++) qf[s] = *(const s16x8*)(qlane + s * 16);

    const ushort* klane = kb + bh * 65536 + lq * 64 + hi * 8;       // row=kv=lq
    const ushort* vlane = vb + (bh * 64 + lq) * 1024 + hi * 8;      // row=d=lq

    float m = -__builtin_inff();
    float lsum = 0.f;
    f32x16 o0 = {}, o1 = {};

    for (int kv0 = 0; kv0 < 1024; kv0 += 64) {
        // ---- K fragments for both 32-kv sub-tiles ----
        const ushort* kpA = klane + kv0 * 64;
        const ushort* kpB = kpA + 32 * 64;
        s16x8 kfA[4], kfB[4];
#pragma unroll
        for (int s = 0; s < 4; s++) {
            kfA[s] = *(const s16x8*)(kpA + s * 16);
            kfB[s] = *(const s16x8*)(kpB + s * 16);
        }

        f32x16 sa = {}, sb = {};
        __builtin_amdgcn_s_setprio(1);
#pragma unroll
        for (int s = 0; s < 4; s++) {
            sa = MFMA32(kfA[s], qf[s], sa);
            sb = MFMA32(kfB[s], qf[s], sb);
        }
        __builtin_amdgcn_s_setprio(0);

        // ---- joint max tree over both tiles (32 values/lane) ----
        float tm[8];
#pragma unroll
        for (int r = 0; r < 8; r++)
            tm[r] = fmaxf(fmaxf(sa[r], sa[r + 8]), fmaxf(sb[r], sb[r + 8]));
#pragma unroll
        for (int s = 4; s; s >>= 1)
#pragma unroll
            for (int r = 0; r < s; r++) tm[r] = fmaxf(tm[r], tm[r + s]);
        const float mx = pairmax(tm[0]);

        if (!__all(mx <= m + 8.f)) {          // defer-max (T13), log2 units
            const float mn = fmaxf(m, mx);
            const float fac = fast_exp2(m - mn);  // first iter: exp2(-inf)=0
            m = mn;
            lsum *= fac;
#pragma unroll
            for (int r = 0; r < 16; r++) { o0[r] *= fac; o1[r] *= fac; }
        }

        float pa[16], pb[16];
#pragma unroll
        for (int r = 0; r < 16; r++) {
            pa[r] = fast_exp2(sa[r] - m);     // bounded by 2^8
            pb[r] = fast_exp2(sb[r] - m);
        }
        float ts[8];
#pragma unroll
        for (int r = 0; r < 8; r++)
            ts[r] = (pa[r] + pa[r + 8]) + (pb[r] + pb[r + 8]);
#pragma unroll
        for (int s = 4; s; s >>= 1)
#pragma unroll
            for (int r = 0; r < s; r++) ts[r] += ts[r + s];
        lsum += pairsum(ts[0]);

        // ---- pack P^T into PV B-fragments (cvt_pk + permlane32_swap) ----
        s16x8 pfA[2], pfB[2];
#pragma unroll
        for (int slot = 0; slot < 2; slot++) {
            const int r0 = slot * 8;
            {
                unsigned a0 = cvtpk_bf16(pa[r0 + 0], pa[r0 + 1]);
                unsigned a1 = cvtpk_bf16(pa[r0 + 4], pa[r0 + 5]);
                plswap(a0, a1);
                unsigned b0 = cvtpk_bf16(pa[r0 + 2], pa[r0 + 3]);
                unsigned b1 = cvtpk_bf16(pa[r0 + 6], pa[r0 + 7]);
                plswap(b0, b1);
                const u32x4 u = {a0, b0, a1, b1};
                pfA[slot] = __builtin_bit_cast(s16x8, u);
            }
            {
                unsigned a0 = cvtpk_bf16(pb[r0 + 0], pb[r0 + 1]);
                unsigned a1 = cvtpk_bf16(pb[r0 + 4], pb[r0 + 5]);
                plswap(a0, a1);
                unsigned b0 = cvtpk_bf16(pb[r0 + 2], pb[r0 + 3]);
                unsigned b1 = cvtpk_bf16(pb[r0 + 6], pb[r0 + 7]);
                plswap(b0, b1);
                const u32x4 u = {a0, b0, a1, b1};
                pfB[slot] = __builtin_bit_cast(s16x8, u);
            }
        }

        // ---- PV: O^T += V^T * P^T  (both sub-tiles) ----
        const ushort* vp0 = vlane + kv0;                // d rows 0..31
        const ushort* vp1 = vp0 + 32 * 1024;            // d rows 32..63
        const s16x8 vA00 = *(const s16x8*)vp0;
        const s16x8 vA01 = *(const s16x8*)(vp0 + 16);
        const s16x8 vB00 = *(const s16x8*)(vp0 + 32);
        const s16x8 vB01 = *(const s16x8*)(vp0 + 48);
        const s16x8 vA10 = *(const s16x8*)vp1;
        const s16x8 vA11 = *(const s16x8*)(vp1 + 16);
        const s16x8 vB10 = *(const s16x8*)(vp1 + 32);
        const s16x8 vB11 = *(const s16x8*)(vp1 + 48);
        __builtin_amdgcn_s_setprio(1);
        o0 = MFMA32(vA00, pfA[0], o0);
        o1 = MFMA32(vA10, pfA[0], o1);
        o0 = MFMA32(vA01, pfA[1], o0);
        o1 = MFMA32(vA11, pfA[1], o1);
        o0 = MFMA32(vB00, pfB[0], o0);
        o1 = MFMA32(vB10, pfB[0], o1);
        o0 = MFMA32(vB01, pfB[1], o0);
        o1 = MFMA32(vB11, pfB[1], o1);
        __builtin_amdgcn_s_setprio(0);
    }

    // ---- epilogue: out[b][q][h*64+d] = O^T[d][q] / lsum ----
    const float inv = 1.f / lsum;
    ushort* op = ao + (b * 1024 + qr0 + lq) * 768 + h * 64 + 4 * hi;
#pragma unroll
    for (int i = 0; i < 4; i++) {
        u16x4 pk0, pk1;
#pragma unroll
        for (int j = 0; j < 4; j++) {
            pk0[j] = f2bf(o0[4 * i + j] * inv);
            pk1[j] = f2bf(o1[4 * i + j] * inv);
        }
        *(u16x4*)(op + 8 * i)      = pk0;   // d = 8i+4hi + 0..3
        *(u16x4*)(op + 32 + 8 * i) = pk1;   // d = 32 + 8i+4hi + 0..3
    }
}

// ---------------------------------------------------------------------------
// Kernel 3: out = attn_out @ proj_w^T + proj_b (fp32 out). grid (64, 6).
// ---------------------------------------------------------------------------
__global__ __launch_bounds__(256) void proj_gemm(
    const ushort* __restrict__ A, const ushort* __restrict__ W,
    const float* __restrict__ bias, float* __restrict__ out)
{
    __shared__ __align__(16) ushort As[128 * 32];
    __shared__ __align__(16) ushort Bs[128 * 32];
    f32x4 acc[4][4];
    const int br = blockIdx.x, bc = blockIdx.y;
    gemm128_mainloop(A, W, 768, br * 128, bc * 128, As, Bs, acc);

    const int t = threadIdx.x, l = t & 63, w = t >> 6;
    const int lr = l & 15, lg = l >> 4, wm = w >> 1, wn = w & 1;
    const int mrow0 = br * 128 + wm * 64 + lg * 4;
    const int ecolB = bc * 128 + wn * 64 + lr;

#pragma unroll
    for (int n = 0; n < 4; n++) {
        const int e = ecolB + n * 16;
        const float bv = bias[e];
#pragma unroll
        for (int m = 0; m < 4; m++) {
            const int mr = mrow0 + m * 16;
#pragma unroll
            for (int r = 0; r < 4; r++)
                out[(mr + r) * 768 + e] = acc[m][n][r] + bv;
        }
    }
}

// ---------------------------------------------------------------------------
extern "C" void kernel_launch(void* const* d_in, const int* in_sizes, int n_in,
                              void* d_out, int out_size, void* d_ws, size_t ws_size,
                              hipStream_t stream)
{
    const float* x  = (const float*)d_in[0];   // [8,1024,768] f32
    const float* wq = (const float*)d_in[1];   // [2304,768]   f32
    const float* wp = (const float*)d_in[2];   // [768,768]    f32
    const float* pb = (const float*)d_in[3];   // [768]        f32
    float* out = (float*)d_out;                // [8,1024,768] f32

    const int NX = 8 * 1024 * 768;             // 6291456
    const int NQ = 2304 * 768;                 // 1769472
    const int NP = 768 * 768;                  // 589824
    const int SEG = 8 * 12 * 1024 * 64;        // 6291456

    ushort* xb  = (ushort*)d_ws;               // x bf16; reused as ao after qkv
    ushort* wqb = xb + NX;
    ushort* wpb = wqb + NQ;
    ushort* qb  = wpb + NP;                    // q  [bh][n][64]  (pre-scaled)
    ushort* kb  = qb + SEG;                    // k  [bh][n][64]
    ushort* vb  = kb + SEG;                    // vT [bh][64][n]
    ushort* ao  = xb;                          // attn out aliases xb (dead by then)

    cvt_f32_bf16<<<2048, 256, 0, stream>>>(x,  xb,  NX / 4);
    cvt_f32_bf16<<<1024, 256, 0, stream>>>(wq, wqb, NQ / 4);
    cvt_f32_bf16<<<576,  256, 0, stream>>>(wp, wpb, NP / 4);

    qkv_gemm  <<<dim3(64, 18), 256, 0, stream>>>(xb, wqb, qb, kb, vb);
    attn_kernel<<<dim3(8, 96), 256, 0, stream>>>(qb, kb, vb, ao);
    proj_gemm <<<dim3(64, 6),  256, 0, stream>>>(ao, wpb, pb, out);
}

// Round 6
// 132.803 us; speedup vs baseline: 1.3714x; 1.3714x over previous
//
#include <hip/hip_runtime.h>

typedef unsigned short ushort;
typedef __attribute__((ext_vector_type(4)))  float  f32x4;
typedef __attribute__((ext_vector_type(16))) float  f32x16;
typedef __attribute__((ext_vector_type(8)))  short  s16x8;
typedef __attribute__((ext_vector_type(4)))  ushort u16x4;
typedef __attribute__((ext_vector_type(4)))  unsigned u32x4;

#define MFMA16(a, b, c) __builtin_amdgcn_mfma_f32_16x16x32_bf16((a), (b), (c), 0, 0, 0)
#define MFMA32(a, b, c) __builtin_amdgcn_mfma_f32_32x32x16_bf16((a), (b), (c), 0, 0, 0)

__device__ __forceinline__ ushort f2bf(float f) {
    unsigned u = __builtin_bit_cast(unsigned, f);
    u = (u + 0x7FFF + ((u >> 16) & 1)) >> 16;   // RNE
    return (ushort)u;
}

__device__ __forceinline__ unsigned cvtpk_bf16(float lo, float hi) {
    unsigned r;
    asm("v_cvt_pk_bf16_f32 %0, %1, %2" : "=v"(r) : "v"(lo), "v"(hi));
    return r;
}
// After the swap: a = [a_lo31 | b_lo31], b = [a_hi31 | b_hi31].
// Only safe when a and b are DISTINCT SSA values (regalloc coalescing hazard).
__device__ __forceinline__ void plswap(unsigned& a, unsigned& b) {
    asm volatile("v_permlane32_swap_b32 %0, %1" : "+v"(a), "+v"(b));
}
__device__ __forceinline__ float pairmax(float x) {
    return fmaxf(x, __shfl_xor(x, 32));
}
__device__ __forceinline__ float pairsum(float x) {
    return x + __shfl_xor(x, 32);
}
// Raw 2^x. exp() folded to exp2 via Q pre-scale by log2(e).
__device__ __forceinline__ float fast_exp2(float x) {
    float r;
    asm("v_exp_f32 %0, %1" : "=v"(r) : "v"(x));
    return r;
}

__device__ __forceinline__ void gload_lds16(const ushort* g, ushort* l) {
    __builtin_amdgcn_global_load_lds(
        (const __attribute__((address_space(1))) void*)g,
        (__attribute__((address_space(3))) void*)l, 16, 0, 0);
}

// ---------------------------------------------------------------------------
// fp32 -> bf16 conversion (grid-stride, float4 in / 8B out)
// ---------------------------------------------------------------------------
__global__ __launch_bounds__(256) void cvt_f32_bf16(
    const float* __restrict__ in, ushort* __restrict__ out, int n4)
{
    int i = blockIdx.x * blockDim.x + threadIdx.x;
    const int stride = gridDim.x * blockDim.x;
    for (; i < n4; i += stride) {
        const float4 v = ((const float4*)in)[i];
        u16x4 o;
        o[0] = f2bf(v.x); o[1] = f2bf(v.y); o[2] = f2bf(v.z); o[3] = f2bf(v.w);
        ((u16x4*)out)[i] = o;
    }
}

// ---------------------------------------------------------------------------
// 128x128 tile GEMM mainloop (m97 structure), unchanged.
// ---------------------------------------------------------------------------
__device__ __forceinline__ void gemm128_mainloop(
    const ushort* __restrict__ A, const ushort* __restrict__ B, int K,
    int row0, int col0, ushort* As, ushort* Bs, f32x4 acc[4][4])
{
    const int t  = threadIdx.x;
    const int l  = t & 63;
    const int w  = t >> 6;
    const int lr = l & 15, lg = l >> 4;
    const int wm = w >> 1, wn = w & 1;

#pragma unroll
    for (int m = 0; m < 4; m++)
#pragma unroll
        for (int n = 0; n < 4; n++) acc[m][n] = (f32x4){0.f, 0.f, 0.f, 0.f};

    const ushort* ga0 = A + (row0 + (t >> 2)) * K + (t & 3) * 8;
    const ushort* gb0 = B + (col0 + (t >> 2)) * K + (t & 3) * 8;
    ushort* la0 = As + t * 8;
    ushort* lb0 = Bs + t * 8;
    const int rowsz = 64 * K;

    for (int k0 = 0; k0 < K; k0 += 32) {
        gload_lds16(ga0 + k0,          la0);
        gload_lds16(ga0 + rowsz + k0,  la0 + 2048);
        gload_lds16(gb0 + k0,          lb0);
        gload_lds16(gb0 + rowsz + k0,  lb0 + 2048);
        __syncthreads();

        s16x8 af[4], bfr[4];
#pragma unroll
        for (int m = 0; m < 4; m++)
            af[m] = *(const s16x8*)&As[(wm * 64 + m * 16 + lr) * 32 + lg * 8];
#pragma unroll
        for (int n = 0; n < 4; n++)
            bfr[n] = *(const s16x8*)&Bs[(wn * 64 + n * 16 + lr) * 32 + lg * 8];
#pragma unroll
        for (int m = 0; m < 4; m++)
#pragma unroll
            for (int n = 0; n < 4; n++)
                acc[m][n] = MFMA16(af[m], bfr[n], acc[m][n]);
        __syncthreads();
    }
}

// ---------------------------------------------------------------------------
// Kernel 1: QKV = x @ qkv_w^T, scatter into q[bh][n][64] (pre-scaled by
// SCALE*log2e so softmax uses exp2), k[bh][n][64], vT[bh][64][n].
// grid (64, 18), block 256.
// ---------------------------------------------------------------------------
__global__ __launch_bounds__(256) void qkv_gemm(
    const ushort* __restrict__ X, const ushort* __restrict__ W,
    ushort* __restrict__ qb, ushort* __restrict__ kb, ushort* __restrict__ vb)
{
    __shared__ __align__(16) ushort As[128 * 32];
    __shared__ __align__(16) ushort Bs[128 * 32];
    f32x4 acc[4][4];
    const int br = blockIdx.x, bc = blockIdx.y;
    gemm128_mainloop(X, W, 768, br * 128, bc * 128, As, Bs, acc);

    const int t = threadIdx.x, l = t & 63, w = t >> 6;
    const int lr = l & 15, lg = l >> 4, wm = w >> 1, wn = w & 1;
    const int p = (bc * 128) / 768;
    const int mrow0 = br * 128 + wm * 64 + lg * 4;
    const int ecolB = bc * 128 + wn * 64 + lr;
    const float QSCALE = 0.125f * 1.44269504088896f;  // SCALE * log2(e)

#pragma unroll
    for (int n = 0; n < 4; n++) {
        const int e   = ecolB + n * 16;
        const int rem = e - p * 768;
        const int h   = rem >> 6;
        const int hd  = rem & 63;
#pragma unroll
        for (int m = 0; m < 4; m++) {
            const int mr = mrow0 + m * 16;
            const int b  = mr >> 10;
            const int nn = mr & 1023;
            const f32x4 v = acc[m][n];
            const int bh = b * 12 + h;
            if (p == 0) {
                ushort* dst = qb + (bh * 1024 + nn) * 64 + hd;
#pragma unroll
                for (int r = 0; r < 4; r++) dst[r * 64] = f2bf(v[r] * QSCALE);
            } else if (p == 1) {
                ushort* dst = kb + (bh * 1024 + nn) * 64 + hd;
#pragma unroll
                for (int r = 0; r < 4; r++) dst[r * 64] = f2bf(v[r]);
            } else {
                u16x4 pk;
                pk[0] = f2bf(v[0]); pk[1] = f2bf(v[1]);
                pk[2] = f2bf(v[2]); pk[3] = f2bf(v[3]);
                *(u16x4*)(vb + (bh * 64 + hd) * 1024 + nn) = pk;
            }
        }
    }
}

// ---------------------------------------------------------------------------
// Kernel 2: flash attention, 32x32 swapped-QK, KVBLK=32.
// grid (96 bh, 8 qt) -> linear wgid = bh + 96*qt -> XCD = bh % 8: all q-tiles
// of one head share an XCD's L2 (12 heads x 256KB = 3MB < 4MB).
// K and V tiles staged in LDS via coalesced global_load_lds, double-buffered,
// XOR-swizzled via pre-swizzled SOURCE addresses (LDS dest stays linear).
// LDS layout per buffer: Ks[32 rows][128B]  row u = K[kv0+u][d 0..63],
//                        Vs[32 rows][128B]  row u = {V[d=u]|V[d=u+32]}[kv 32],
// both with content(row, p) = src(row, p ^ ((row&7)<<4)).
// ---------------------------------------------------------------------------
__global__ __launch_bounds__(256) void attn_kernel(
    const ushort* __restrict__ qb, const ushort* __restrict__ kb,
    const ushort* __restrict__ vb, ushort* __restrict__ ao)
{
    __shared__ __align__(16) ushort KV[2][4096];   // [buf][K 2048 | V 2048] = 16KB
    const int bh = blockIdx.x, qt = blockIdx.y;
    const int b = bh / 12, h = bh - b * 12;
    const int t = threadIdx.x, l = t & 63, w = t >> 6;
    const int lq = l & 31, hi = l >> 5;
    const int qr0 = qt * 128 + w * 32;

    // ---- staging source addresses (pre-swizzled) ----
    const int l3 = l >> 3, l7 = l & 7;
    const int ku = w * 8 + l3;                      // LDS row this lane fills
    const int pfv = l7 ^ l3;                        // swizzled 16B slot index
    const char* ksrc = (const char*)kb + (size_t)(bh * 1024 + ku) * 128
                     + ((l7 ^ l3) << 4);            // + kv0*128 per iter
    const char* vsrc = (const char*)vb + (size_t)(bh * 64 + ku + 32 * ((pfv >> 2) & 1)) * 2048
                     + ((pfv & 3) << 4);            // + kv0*2 per iter
    ushort* kdst = &KV[0][0]    + w * 512 + l * 8;  // uniform base + lane*16B
    ushort* vdst = &KV[0][2048] + w * 512 + l * 8;

    // ---- Q fragments (B-operand): col=q=lq, k=d-slice s*16 + hi*8 ----
    const ushort* qlane = qb + (bh * 1024 + qr0 + lq) * 64 + hi * 8;
    s16x8 qf[4];
#pragma unroll
    for (int s = 0; s < 4; s++) qf[s] = *(const s16x8*)(qlane + s * 16);

    float m = -__builtin_inff();
    float lsum = 0.f;
    f32x16 o0 = {}, o1 = {};

    // prologue: stage tile 0 into buf 0
    gload_lds16((const ushort*)ksrc, kdst);
    gload_lds16((const ushort*)vsrc, vdst);
    __syncthreads();

    const int fx = (lq & 7) << 4;                   // read-side swizzle
    for (int it = 0; it < 32; ++it) {
        const int cur = it & 1;
        // ---- prefetch next tile into the other buffer ----
        if (it < 31) {
            const int kvn = (it + 1) * 32;
            gload_lds16((const ushort*)(ksrc + kvn * 128), kdst + (cur ^ 1) * 4096);
            gload_lds16((const ushort*)(vsrc + kvn * 2),   vdst + (cur ^ 1) * 4096);
        }
        const char* Kb = (const char*)&KV[cur][0];
        const char* Vb = (const char*)&KV[cur][2048];

        // ---- K fragments (A-operand): row kv=lq, d-slice s*16+hi*8 ----
        s16x8 kf[4];
#pragma unroll
        for (int s = 0; s < 4; s++)
            kf[s] = *(const s16x8*)(Kb + lq * 128 + ((hi * 16 + s * 32) ^ fx));

        f32x16 sa = {};
        __builtin_amdgcn_s_setprio(1);
#pragma unroll
        for (int s = 0; s < 4; s++) sa = MFMA32(kf[s], qf[s], sa);
        __builtin_amdgcn_s_setprio(0);

        // ---- in-register online softmax (16 k/lane, pair lane has rest) ----
        float tm[8];
#pragma unroll
        for (int r = 0; r < 8; r++) tm[r] = fmaxf(sa[r], sa[r + 8]);
#pragma unroll
        for (int s = 4; s; s >>= 1)
#pragma unroll
            for (int r = 0; r < s; r++) tm[r] = fmaxf(tm[r], tm[r + s]);
        const float mx = pairmax(tm[0]);

        if (!__all(mx <= m + 8.f)) {          // defer-max (T13), log2 units
            const float mn = fmaxf(m, mx);
            const float fac = fast_exp2(m - mn);
            m = mn;
            lsum *= fac;
#pragma unroll
            for (int r = 0; r < 16; r++) { o0[r] *= fac; o1[r] *= fac; }
        }

        float p[16];
#pragma unroll
        for (int r = 0; r < 16; r++) p[r] = fast_exp2(sa[r] - m);
        float ts[8];
#pragma unroll
        for (int r = 0; r < 8; r++) ts[r] = p[r] + p[r + 8];
#pragma unroll
        for (int s = 4; s; s >>= 1)
#pragma unroll
            for (int r = 0; r < s; r++) ts[r] += ts[r + s];
        lsum += pairsum(ts[0]);

        // ---- pack P^T into PV B-fragments (cvt_pk + permlane32_swap) ----
        s16x8 pfr[2];
#pragma unroll
        for (int slot = 0; slot < 2; slot++) {
            const int r0 = slot * 8;
            unsigned a0 = cvtpk_bf16(p[r0 + 0], p[r0 + 1]);
            unsigned a1 = cvtpk_bf16(p[r0 + 4], p[r0 + 5]);
            plswap(a0, a1);
            unsigned b0 = cvtpk_bf16(p[r0 + 2], p[r0 + 3]);
            unsigned b1 = cvtpk_bf16(p[r0 + 6], p[r0 + 7]);
            plswap(b0, b1);
            const u32x4 u = {a0, b0, a1, b1};
            pfr[slot] = __builtin_bit_cast(s16x8, u);
        }

        // ---- V fragments + PV: O^T += V^T * P^T ----
        s16x8 vf[2][2];   // [half d0/d32][k-slot]
#pragma unroll
        for (int half = 0; half < 2; half++)
#pragma unroll
            for (int s = 0; s < 2; s++)
                vf[half][s] = *(const s16x8*)(Vb + lq * 128 + ((half * 64 + hi * 16 + s * 32) ^ fx));
        __builtin_amdgcn_s_setprio(1);
        o0 = MFMA32(vf[0][0], pfr[0], o0);
        o1 = MFMA32(vf[1][0], pfr[0], o1);
        o0 = MFMA32(vf[0][1], pfr[1], o0);
        o1 = MFMA32(vf[1][1], pfr[1], o1);
        __builtin_amdgcn_s_setprio(0);

        __syncthreads();   // drains prefetch (vmcnt) + all reads of cur buf
    }

    // ---- epilogue: out[b][q][h*64+d] = O^T[d][q] / lsum ----
    const float inv = 1.f / lsum;
    ushort* op = ao + (b * 1024 + qr0 + lq) * 768 + h * 64 + 4 * hi;
#pragma unroll
    for (int i = 0; i < 4; i++) {
        u16x4 pk0, pk1;
#pragma unroll
        for (int j = 0; j < 4; j++) {
            pk0[j] = f2bf(o0[4 * i + j] * inv);
            pk1[j] = f2bf(o1[4 * i + j] * inv);
        }
        *(u16x4*)(op + 8 * i)      = pk0;   // d = 8i+4hi + 0..3
        *(u16x4*)(op + 32 + 8 * i) = pk1;   // d = 32 + 8i+4hi + 0..3
    }
}

// ---------------------------------------------------------------------------
// Kernel 3: out = attn_out @ proj_w^T + proj_b (fp32 out). grid (64, 6).
// ---------------------------------------------------------------------------
__global__ __launch_bounds__(256) void proj_gemm(
    const ushort* __restrict__ A, const ushort* __restrict__ W,
    const float* __restrict__ bias, float* __restrict__ out)
{
    __shared__ __align__(16) ushort As[128 * 32];
    __shared__ __align__(16) ushort Bs[128 * 32];
    f32x4 acc[4][4];
    const int br = blockIdx.x, bc = blockIdx.y;
    gemm128_mainloop(A, W, 768, br * 128, bc * 128, As, Bs, acc);

    const int t = threadIdx.x, l = t & 63, w = t >> 6;
    const int lr = l & 15, lg = l >> 4, wm = w >> 1, wn = w & 1;
    const int mrow0 = br * 128 + wm * 64 + lg * 4;
    const int ecolB = bc * 128 + wn * 64 + lr;

#pragma unroll
    for (int n = 0; n < 4; n++) {
        const int e = ecolB + n * 16;
        const float bv = bias[e];
#pragma unroll
        for (int m = 0; m < 4; m++) {
            const int mr = mrow0 + m * 16;
#pragma unroll
            for (int r = 0; r < 4; r++)
                out[(mr + r) * 768 + e] = acc[m][n][r] + bv;
        }
    }
}

// ---------------------------------------------------------------------------
extern "C" void kernel_launch(void* const* d_in, const int* in_sizes, int n_in,
                              void* d_out, int out_size, void* d_ws, size_t ws_size,
                              hipStream_t stream)
{
    const float* x  = (const float*)d_in[0];   // [8,1024,768] f32
    const float* wq = (const float*)d_in[1];   // [2304,768]   f32
    const float* wp = (const float*)d_in[2];   // [768,768]    f32
    const float* pb = (const float*)d_in[3];   // [768]        f32
    float* out = (float*)d_out;                // [8,1024,768] f32

    const int NX = 8 * 1024 * 768;             // 6291456
    const int NQ = 2304 * 768;                 // 1769472
    const int NP = 768 * 768;                  // 589824
    const int SEG = 8 * 12 * 1024 * 64;        // 6291456

    ushort* xb  = (ushort*)d_ws;               // x bf16; reused as ao after qkv
    ushort* wqb = xb + NX;
    ushort* wpb = wqb + NQ;
    ushort* qb  = wpb + NP;                    // q  [bh][n][64]  (pre-scaled)
    ushort* kb  = qb + SEG;                    // k  [bh][n][64]
    ushort* vb  = kb + SEG;                    // vT [bh][64][n]
    ushort* ao  = xb;                          // attn out aliases xb (dead by then)

    cvt_f32_bf16<<<2048, 256, 0, stream>>>(x,  xb,  NX / 4);
    cvt_f32_bf16<<<1024, 256, 0, stream>>>(wq, wqb, NQ / 4);
    cvt_f32_bf16<<<576,  256, 0, stream>>>(wp, wpb, NP / 4);

    qkv_gemm  <<<dim3(64, 18), 256, 0, stream>>>(xb, wqb, qb, kb, vb);
    attn_kernel<<<dim3(96, 8), 256, 0, stream>>>(qb, kb, vb, ao);
    proj_gemm <<<dim3(64, 6),  256, 0, stream>>>(ao, wpb, pb, out);
}

// Round 7
// 128.379 us; speedup vs baseline: 1.4186x; 1.0345x over previous
//
#include <hip/hip_runtime.h>

typedef unsigned short ushort;
typedef __attribute__((ext_vector_type(4)))  float  f32x4;
typedef __attribute__((ext_vector_type(16))) float  f32x16;
typedef __attribute__((ext_vector_type(8)))  short  s16x8;
typedef __attribute__((ext_vector_type(4)))  ushort u16x4;
typedef __attribute__((ext_vector_type(4)))  unsigned u32x4;

#define MFMA16(a, b, c) __builtin_amdgcn_mfma_f32_16x16x32_bf16((a), (b), (c), 0, 0, 0)
#define MFMA32(a, b, c) __builtin_amdgcn_mfma_f32_32x32x16_bf16((a), (b), (c), 0, 0, 0)

__device__ __forceinline__ ushort f2bf(float f) {
    unsigned u = __builtin_bit_cast(unsigned, f);
    u = (u + 0x7FFF + ((u >> 16) & 1)) >> 16;   // RNE
    return (ushort)u;
}

__device__ __forceinline__ unsigned cvtpk_bf16(float lo, float hi) {
    unsigned r;
    asm("v_cvt_pk_bf16_f32 %0, %1, %2" : "=v"(r) : "v"(lo), "v"(hi));
    return r;
}
// After the swap: a = [a_lo31 | b_lo31], b = [a_hi31 | b_hi31].
// Only safe when a and b are DISTINCT SSA values (regalloc coalescing hazard).
__device__ __forceinline__ void plswap(unsigned& a, unsigned& b) {
    asm volatile("v_permlane32_swap_b32 %0, %1" : "+v"(a), "+v"(b));
}
__device__ __forceinline__ float pairmax(float x) {
    return fmaxf(x, __shfl_xor(x, 32));
}
__device__ __forceinline__ float pairsum(float x) {
    return x + __shfl_xor(x, 32);
}
// Raw 2^x. exp() folded to exp2 via Q pre-scale by log2(e).
__device__ __forceinline__ float fast_exp2(float x) {
    float r;
    asm("v_exp_f32 %0, %1" : "=v"(r) : "v"(x));
    return r;
}

__device__ __forceinline__ void gload_lds16(const ushort* g, ushort* l) {
    __builtin_amdgcn_global_load_lds(
        (const __attribute__((address_space(1))) void*)g,
        (__attribute__((address_space(3))) void*)l, 16, 0, 0);
}

// ---------------------------------------------------------------------------
// fp32 -> bf16 conversion (grid-stride, float4 in / 8B out)
// ---------------------------------------------------------------------------
__global__ __launch_bounds__(256) void cvt_f32_bf16(
    const float* __restrict__ in, ushort* __restrict__ out, int n4)
{
    int i = blockIdx.x * blockDim.x + threadIdx.x;
    const int stride = gridDim.x * blockDim.x;
    for (; i < n4; i += stride) {
        const float4 v = ((const float4*)in)[i];
        u16x4 o;
        o[0] = f2bf(v.x); o[1] = f2bf(v.y); o[2] = f2bf(v.z); o[3] = f2bf(v.w);
        ((u16x4*)out)[i] = o;
    }
}

// ---------------------------------------------------------------------------
// 128x128 tile GEMM mainloop, double-buffered (T3-minimum 2-phase):
// stage tile t+1 BEFORE computing tile t; one barrier per step.
// As/Bs are 2-buffer arrays of 2*4096 ushorts each (32 KB LDS total).
// C[row0..+128][col0..+128] += A[M][K] * B[N][K]^T, k-contiguous bf16.
// 256 thr = 4 waves 2x2; each wave computes a 64x64 sub-tile (acc[4][4]).
// ---------------------------------------------------------------------------
__device__ __forceinline__ void gemm128_mainloop(
    const ushort* __restrict__ A, const ushort* __restrict__ B, int K,
    int row0, int col0, ushort* As, ushort* Bs, f32x4 acc[4][4])
{
    const int t  = threadIdx.x;
    const int l  = t & 63;
    const int w  = t >> 6;
    const int lr = l & 15, lg = l >> 4;
    const int wm = w >> 1, wn = w & 1;

#pragma unroll
    for (int m = 0; m < 4; m++)
#pragma unroll
        for (int n = 0; n < 4; n++) acc[m][n] = (f32x4){0.f, 0.f, 0.f, 0.f};

    const ushort* ga0 = A + (row0 + (t >> 2)) * K + (t & 3) * 8;
    const ushort* gb0 = B + (col0 + (t >> 2)) * K + (t & 3) * 8;
    const int rowsz = 64 * K;
    ushort* la0 = As + t * 8;
    ushort* lb0 = Bs + t * 8;

    // prologue: stage tile 0 into buffer 0
    gload_lds16(ga0,         la0);
    gload_lds16(ga0 + rowsz, la0 + 2048);
    gload_lds16(gb0,         lb0);
    gload_lds16(gb0 + rowsz, lb0 + 2048);
    __syncthreads();

    const int nt = K >> 5;
    for (int it = 0; it < nt; ++it) {
        const int cur = it & 1;
        // ---- prefetch tile it+1 into the other buffer (loads in flight
        //      across the compute below; drained by the end barrier) ----
        if (it + 1 < nt) {
            const int k0  = (it + 1) * 32;
            const int nxt = (cur ^ 1) * 4096;
            gload_lds16(ga0 + k0,         la0 + nxt);
            gload_lds16(ga0 + rowsz + k0, la0 + nxt + 2048);
            gload_lds16(gb0 + k0,         lb0 + nxt);
            gload_lds16(gb0 + rowsz + k0, lb0 + nxt + 2048);
        }
        const ushort* Ab = As + cur * 4096;
        const ushort* Bb = Bs + cur * 4096;

        s16x8 af[4], bfr[4];
#pragma unroll
        for (int m = 0; m < 4; m++)
            af[m] = *(const s16x8*)&Ab[(wm * 64 + m * 16 + lr) * 32 + lg * 8];
#pragma unroll
        for (int n = 0; n < 4; n++)
            bfr[n] = *(const s16x8*)&Bb[(wn * 64 + n * 16 + lr) * 32 + lg * 8];
        __builtin_amdgcn_s_setprio(1);
#pragma unroll
        for (int m = 0; m < 4; m++)
#pragma unroll
            for (int n = 0; n < 4; n++)
                acc[m][n] = MFMA16(af[m], bfr[n], acc[m][n]);
        __builtin_amdgcn_s_setprio(0);
        __syncthreads();   // drains prefetch vmcnt + all reads of cur buffer
    }
}

// ---------------------------------------------------------------------------
// Kernel 1: QKV = x @ qkv_w^T, scatter into q[bh][n][64] (pre-scaled by
// SCALE*log2e so softmax uses exp2), k[bh][n][64], vT[bh][64][n].
// grid (64, 18), block 256.
// ---------------------------------------------------------------------------
__global__ __launch_bounds__(256) void qkv_gemm(
    const ushort* __restrict__ X, const ushort* __restrict__ W,
    ushort* __restrict__ qb, ushort* __restrict__ kb, ushort* __restrict__ vb)
{
    __shared__ __align__(16) ushort As[2 * 128 * 32];
    __shared__ __align__(16) ushort Bs[2 * 128 * 32];
    f32x4 acc[4][4];
    const int br = blockIdx.x, bc = blockIdx.y;
    gemm128_mainloop(X, W, 768, br * 128, bc * 128, As, Bs, acc);

    const int t = threadIdx.x, l = t & 63, w = t >> 6;
    const int lr = l & 15, lg = l >> 4, wm = w >> 1, wn = w & 1;
    const int p = (bc * 128) / 768;
    const int mrow0 = br * 128 + wm * 64 + lg * 4;
    const int ecolB = bc * 128 + wn * 64 + lr;
    const float QSCALE = 0.125f * 1.44269504088896f;  // SCALE * log2(e)

#pragma unroll
    for (int n = 0; n < 4; n++) {
        const int e   = ecolB + n * 16;
        const int rem = e - p * 768;
        const int h   = rem >> 6;
        const int hd  = rem & 63;
#pragma unroll
        for (int m = 0; m < 4; m++) {
            const int mr = mrow0 + m * 16;
            const int b  = mr >> 10;
            const int nn = mr & 1023;
            const f32x4 v = acc[m][n];
            const int bh = b * 12 + h;
            if (p == 0) {
                ushort* dst = qb + (bh * 1024 + nn) * 64 + hd;
#pragma unroll
                for (int r = 0; r < 4; r++) dst[r * 64] = f2bf(v[r] * QSCALE);
            } else if (p == 1) {
                ushort* dst = kb + (bh * 1024 + nn) * 64 + hd;
#pragma unroll
                for (int r = 0; r < 4; r++) dst[r * 64] = f2bf(v[r]);
            } else {
                u16x4 pk;
                pk[0] = f2bf(v[0]); pk[1] = f2bf(v[1]);
                pk[2] = f2bf(v[2]); pk[3] = f2bf(v[3]);
                *(u16x4*)(vb + (bh * 64 + hd) * 1024 + nn) = pk;
            }
        }
    }
}

// ---------------------------------------------------------------------------
// Kernel 2: flash attention, 32x32 swapped-QK, KVBLK=32 (unchanged from R6).
// grid (96 bh, 8 qt); K/V staged in LDS (coalesced gload_lds, double-buffered,
// source-side XOR swizzle), block-shared; softmax fully in-register.
// ---------------------------------------------------------------------------
__global__ __launch_bounds__(256) void attn_kernel(
    const ushort* __restrict__ qb, const ushort* __restrict__ kb,
    const ushort* __restrict__ vb, ushort* __restrict__ ao)
{
    __shared__ __align__(16) ushort KV[2][4096];   // [buf][K 2048 | V 2048] = 16KB
    const int bh = blockIdx.x, qt = blockIdx.y;
    const int b = bh / 12, h = bh - b * 12;
    const int t = threadIdx.x, l = t & 63, w = t >> 6;
    const int lq = l & 31, hi = l >> 5;
    const int qr0 = qt * 128 + w * 32;

    // ---- staging source addresses (pre-swizzled) ----
    const int l3 = l >> 3, l7 = l & 7;
    const int ku = w * 8 + l3;                      // LDS row this lane fills
    const int pfv = l7 ^ l3;                        // swizzled 16B slot index
    const char* ksrc = (const char*)kb + (size_t)(bh * 1024 + ku) * 128
                     + ((l7 ^ l3) << 4);            // + kv0*128 per iter
    const char* vsrc = (const char*)vb + (size_t)(bh * 64 + ku + 32 * ((pfv >> 2) & 1)) * 2048
                     + ((pfv & 3) << 4);            // + kv0*2 per iter
    ushort* kdst = &KV[0][0]    + w * 512 + l * 8;  // uniform base + lane*16B
    ushort* vdst = &KV[0][2048] + w * 512 + l * 8;

    // ---- Q fragments (B-operand): col=q=lq, k=d-slice s*16 + hi*8 ----
    const ushort* qlane = qb + (bh * 1024 + qr0 + lq) * 64 + hi * 8;
    s16x8 qf[4];
#pragma unroll
    for (int s = 0; s < 4; s++) qf[s] = *(const s16x8*)(qlane + s * 16);

    float m = -__builtin_inff();
    float lsum = 0.f;
    f32x16 o0 = {}, o1 = {};

    // prologue: stage tile 0 into buf 0
    gload_lds16((const ushort*)ksrc, kdst);
    gload_lds16((const ushort*)vsrc, vdst);
    __syncthreads();

    const int fx = (lq & 7) << 4;                   // read-side swizzle
    for (int it = 0; it < 32; ++it) {
        const int cur = it & 1;
        // ---- prefetch next tile into the other buffer ----
        if (it < 31) {
            const int kvn = (it + 1) * 32;
            gload_lds16((const ushort*)(ksrc + kvn * 128), kdst + (cur ^ 1) * 4096);
            gload_lds16((const ushort*)(vsrc + kvn * 2),   vdst + (cur ^ 1) * 4096);
        }
        const char* Kb = (const char*)&KV[cur][0];
        const char* Vb = (const char*)&KV[cur][2048];

        // ---- K fragments (A-operand): row kv=lq, d-slice s*16+hi*8 ----
        s16x8 kf[4];
#pragma unroll
        for (int s = 0; s < 4; s++)
            kf[s] = *(const s16x8*)(Kb + lq * 128 + ((hi * 16 + s * 32) ^ fx));

        f32x16 sa = {};
        __builtin_amdgcn_s_setprio(1);
#pragma unroll
        for (int s = 0; s < 4; s++) sa = MFMA32(kf[s], qf[s], sa);
        __builtin_amdgcn_s_setprio(0);

        // ---- in-register online softmax (16 k/lane, pair lane has rest) ----
        float tm[8];
#pragma unroll
        for (int r = 0; r < 8; r++) tm[r] = fmaxf(sa[r], sa[r + 8]);
#pragma unroll
        for (int s = 4; s; s >>= 1)
#pragma unroll
            for (int r = 0; r < s; r++) tm[r] = fmaxf(tm[r], tm[r + s]);
        const float mx = pairmax(tm[0]);

        if (!__all(mx <= m + 8.f)) {          // defer-max (T13), log2 units
            const float mn = fmaxf(m, mx);
            const float fac = fast_exp2(m - mn);
            m = mn;
            lsum *= fac;
#pragma unroll
            for (int r = 0; r < 16; r++) { o0[r] *= fac; o1[r] *= fac; }
        }

        float p[16];
#pragma unroll
        for (int r = 0; r < 16; r++) p[r] = fast_exp2(sa[r] - m);
        float ts[8];
#pragma unroll
        for (int r = 0; r < 8; r++) ts[r] = p[r] + p[r + 8];
#pragma unroll
        for (int s = 4; s; s >>= 1)
#pragma unroll
            for (int r = 0; r < s; r++) ts[r] += ts[r + s];
        lsum += pairsum(ts[0]);

        // ---- pack P^T into PV B-fragments (cvt_pk + permlane32_swap) ----
        s16x8 pfr[2];
#pragma unroll
        for (int slot = 0; slot < 2; slot++) {
            const int r0 = slot * 8;
            unsigned a0 = cvtpk_bf16(p[r0 + 0], p[r0 + 1]);
            unsigned a1 = cvtpk_bf16(p[r0 + 4], p[r0 + 5]);
            plswap(a0, a1);
            unsigned b0 = cvtpk_bf16(p[r0 + 2], p[r0 + 3]);
            unsigned b1 = cvtpk_bf16(p[r0 + 6], p[r0 + 7]);
            plswap(b0, b1);
            const u32x4 u = {a0, b0, a1, b1};
            pfr[slot] = __builtin_bit_cast(s16x8, u);
        }

        // ---- V fragments + PV: O^T += V^T * P^T ----
        s16x8 vf[2][2];   // [half d0/d32][k-slot]
#pragma unroll
        for (int half = 0; half < 2; half++)
#pragma unroll
            for (int s = 0; s < 2; s++)
                vf[half][s] = *(const s16x8*)(Vb + lq * 128 + ((half * 64 + hi * 16 + s * 32) ^ fx));
        __builtin_amdgcn_s_setprio(1);
        o0 = MFMA32(vf[0][0], pfr[0], o0);
        o1 = MFMA32(vf[1][0], pfr[0], o1);
        o0 = MFMA32(vf[0][1], pfr[1], o0);
        o1 = MFMA32(vf[1][1], pfr[1], o1);
        __builtin_amdgcn_s_setprio(0);

        __syncthreads();   // drains prefetch (vmcnt) + all reads of cur buf
    }

    // ---- epilogue: out[b][q][h*64+d] = O^T[d][q] / lsum ----
    const float inv = 1.f / lsum;
    ushort* op = ao + (b * 1024 + qr0 + lq) * 768 + h * 64 + 4 * hi;
#pragma unroll
    for (int i = 0; i < 4; i++) {
        u16x4 pk0, pk1;
#pragma unroll
        for (int j = 0; j < 4; j++) {
            pk0[j] = f2bf(o0[4 * i + j] * inv);
            pk1[j] = f2bf(o1[4 * i + j] * inv);
        }
        *(u16x4*)(op + 8 * i)      = pk0;   // d = 8i+4hi + 0..3
        *(u16x4*)(op + 32 + 8 * i) = pk1;   // d = 32 + 8i+4hi + 0..3
    }
}

// ---------------------------------------------------------------------------
// Kernel 3: out = attn_out @ proj_w^T + proj_b (fp32 out). grid (64, 6).
// ---------------------------------------------------------------------------
__global__ __launch_bounds__(256) void proj_gemm(
    const ushort* __restrict__ A, const ushort* __restrict__ W,
    const float* __restrict__ bias, float* __restrict__ out)
{
    __shared__ __align__(16) ushort As[2 * 128 * 32];
    __shared__ __align__(16) ushort Bs[2 * 128 * 32];
    f32x4 acc[4][4];
    const int br = blockIdx.x, bc = blockIdx.y;
    gemm128_mainloop(A, W, 768, br * 128, bc * 128, As, Bs, acc);

    const int t = threadIdx.x, l = t & 63, w = t >> 6;
    const int lr = l & 15, lg = l >> 4, wm = w >> 1, wn = w & 1;
    const int mrow0 = br * 128 + wm * 64 + lg * 4;
    const int ecolB = bc * 128 + wn * 64 + lr;

#pragma unroll
    for (int n = 0; n < 4; n++) {
        const int e = ecolB + n * 16;
        const float bv = bias[e];
#pragma unroll
        for (int m = 0; m < 4; m++) {
            const int mr = mrow0 + m * 16;
#pragma unroll
            for (int r = 0; r < 4; r++)
                out[(mr + r) * 768 + e] = acc[m][n][r] + bv;
        }
    }
}

// ---------------------------------------------------------------------------
extern "C" void kernel_launch(void* const* d_in, const int* in_sizes, int n_in,
                              void* d_out, int out_size, void* d_ws, size_t ws_size,
                              hipStream_t stream)
{
    const float* x  = (const float*)d_in[0];   // [8,1024,768] f32
    const float* wq = (const float*)d_in[1];   // [2304,768]   f32
    const float* wp = (const float*)d_in[2];   // [768,768]    f32
    const float* pb = (const float*)d_in[3];   // [768]        f32
    float* out = (float*)d_out;                // [8,1024,768] f32

    const int NX = 8 * 1024 * 768;             // 6291456
    const int NQ = 2304 * 768;                 // 1769472
    const int NP = 768 * 768;                  // 589824
    const int SEG = 8 * 12 * 1024 * 64;        // 6291456

    ushort* xb  = (ushort*)d_ws;               // x bf16; reused as ao after qkv
    ushort* wqb = xb + NX;
    ushort* wpb = wqb + NQ;
    ushort* qb  = wpb + NP;                    // q  [bh][n][64]  (pre-scaled)
    ushort* kb  = qb + SEG;                    // k  [bh][n][64]
    ushort* vb  = kb + SEG;                    // vT [bh][64][n]
    ushort* ao  = xb;                          // attn out aliases xb (dead by then)

    cvt_f32_bf16<<<2048, 256, 0, stream>>>(x,  xb,  NX / 4);
    cvt_f32_bf16<<<1024, 256, 0, stream>>>(wq, wqb, NQ / 4);
    cvt_f32_bf16<<<576,  256, 0, stream>>>(wp, wpb, NP / 4);

    qkv_gemm  <<<dim3(64, 18), 256, 0, stream>>>(xb, wqb, qb, kb, vb);
    attn_kernel<<<dim3(96, 8), 256, 0, stream>>>(qb, kb, vb, ao);
    proj_gemm <<<dim3(64, 6),  256, 0, stream>>>(ao, wpb, pb, out);
}

// Round 8
// 120.820 us; speedup vs baseline: 1.5074x; 1.0626x over previous
//
#include <hip/hip_runtime.h>

typedef unsigned short ushort;
typedef __attribute__((ext_vector_type(4)))  float  f32x4;
typedef __attribute__((ext_vector_type(16))) float  f32x16;
typedef __attribute__((ext_vector_type(8)))  short  s16x8;
typedef __attribute__((ext_vector_type(4)))  ushort u16x4;
typedef __attribute__((ext_vector_type(4)))  unsigned u32x4;

#define MFMA16(a, b, c) __builtin_amdgcn_mfma_f32_16x16x32_bf16((a), (b), (c), 0, 0, 0)
#define MFMA32(a, b, c) __builtin_amdgcn_mfma_f32_32x32x16_bf16((a), (b), (c), 0, 0, 0)

__device__ __forceinline__ ushort f2bf(float f) {
    unsigned u = __builtin_bit_cast(unsigned, f);
    u = (u + 0x7FFF + ((u >> 16) & 1)) >> 16;   // RNE
    return (ushort)u;
}

__device__ __forceinline__ unsigned cvtpk_bf16(float lo, float hi) {
    unsigned r;
    asm("v_cvt_pk_bf16_f32 %0, %1, %2" : "=v"(r) : "v"(lo), "v"(hi));
    return r;
}
// After the swap: a = [a_lo31 | b_lo31], b = [a_hi31 | b_hi31].
// Only safe when a and b are DISTINCT SSA values (regalloc coalescing hazard).
__device__ __forceinline__ void plswap(unsigned& a, unsigned& b) {
    asm volatile("v_permlane32_swap_b32 %0, %1" : "+v"(a), "+v"(b));
}
__device__ __forceinline__ float pairmax(float x) {
    return fmaxf(x, __shfl_xor(x, 32));
}
__device__ __forceinline__ float pairsum(float x) {
    return x + __shfl_xor(x, 32);
}
// Raw 2^x. exp() folded to exp2 via Q pre-scale by log2(e).
__device__ __forceinline__ float fast_exp2(float x) {
    float r;
    asm("v_exp_f32 %0, %1" : "=v"(r) : "v"(x));
    return r;
}

__device__ __forceinline__ void gload_lds16(const ushort* g, ushort* l) {
    __builtin_amdgcn_global_load_lds(
        (const __attribute__((address_space(1))) void*)g,
        (__attribute__((address_space(3))) void*)l, 16, 0, 0);
}

// ---------------------------------------------------------------------------
// fp32 -> bf16 conversion (grid-stride, float4 in / 8B out)
// ---------------------------------------------------------------------------
__global__ __launch_bounds__(256) void cvt_f32_bf16(
    const float* __restrict__ in, ushort* __restrict__ out, int n4)
{
    int i = blockIdx.x * blockDim.x + threadIdx.x;
    const int stride = gridDim.x * blockDim.x;
    for (; i < n4; i += stride) {
        const float4 v = ((const float4*)in)[i];
        u16x4 o;
        o[0] = f2bf(v.x); o[1] = f2bf(v.y); o[2] = f2bf(v.z); o[3] = f2bf(v.w);
        ((u16x4*)out)[i] = o;
    }
}

// ---------------------------------------------------------------------------
// 128x128 tile GEMM mainloop, 3-buffer / 2-deep prefetch / counted vmcnt (T4):
// at iteration it: stage tile it+2 into buf (it+2)%3, compute buf it%3, then
// `s_waitcnt vmcnt(4)` + raw s_barrier -- the newest stage's 4 loads remain
// in flight across the barrier (2-iteration latency window per load).
// Requires K%96==0 (nt divisible by 3); K=768 here.
// As/Bs: 3 buffers x 4096 ushorts each (48 KB LDS total).
// ---------------------------------------------------------------------------
__device__ __forceinline__ void gemm128_mainloop(
    const ushort* __restrict__ A, const ushort* __restrict__ B, int K,
    int row0, int col0, ushort* As, ushort* Bs, f32x4 acc[4][4])
{
    const int t  = threadIdx.x;
    const int l  = t & 63;
    const int w  = t >> 6;
    const int lr = l & 15, lg = l >> 4;
    const int wm = w >> 1, wn = w & 1;

#pragma unroll
    for (int m = 0; m < 4; m++)
#pragma unroll
        for (int n = 0; n < 4; n++) acc[m][n] = (f32x4){0.f, 0.f, 0.f, 0.f};

    const ushort* ga0 = A + (row0 + (t >> 2)) * K + (t & 3) * 8;
    const ushort* gb0 = B + (col0 + (t >> 2)) * K + (t & 3) * 8;
    const int rowsz = 64 * K;
    ushort* la0 = As + t * 8;
    ushort* lb0 = Bs + t * 8;

    auto STAGE = [&](int kt, int buf) {
        const int k0  = kt * 32;
        const int off = buf * 4096;
        gload_lds16(ga0 + k0,         la0 + off);
        gload_lds16(ga0 + rowsz + k0, la0 + off + 2048);
        gload_lds16(gb0 + k0,         lb0 + off);
        gload_lds16(gb0 + rowsz + k0, lb0 + off + 2048);
    };
    auto COMPUTE = [&](int buf) {
        const ushort* Ab = As + buf * 4096;
        const ushort* Bb = Bs + buf * 4096;
        s16x8 af[4], bfr[4];
#pragma unroll
        for (int m = 0; m < 4; m++)
            af[m] = *(const s16x8*)&Ab[(wm * 64 + m * 16 + lr) * 32 + lg * 8];
#pragma unroll
        for (int n = 0; n < 4; n++)
            bfr[n] = *(const s16x8*)&Bb[(wn * 64 + n * 16 + lr) * 32 + lg * 8];
        __builtin_amdgcn_s_setprio(1);
#pragma unroll
        for (int m = 0; m < 4; m++)
#pragma unroll
            for (int n = 0; n < 4; n++)
                acc[m][n] = MFMA16(af[m], bfr[n], acc[m][n]);
        __builtin_amdgcn_s_setprio(0);
    };

    const int nt = K >> 5;          // 24; must be divisible by 3
    // prologue: tiles 0,1 in flight
    STAGE(0, 0);
    STAGE(1, 1);
    asm volatile("s_waitcnt vmcnt(4)" ::: "memory");   // tile0 landed
    __builtin_amdgcn_s_barrier();

#define GSTEP(IT, CBUF, SBUF)                                          \
    {                                                                  \
        const int sk = (IT) + 2;                                       \
        const bool st = sk < nt;                                       \
        if (st) STAGE(sk, SBUF);                                       \
        COMPUTE(CBUF);                                                 \
        if (st) { asm volatile("s_waitcnt vmcnt(4)" ::: "memory"); }   \
        else    { asm volatile("s_waitcnt vmcnt(0)" ::: "memory"); }   \
        __builtin_amdgcn_s_barrier();                                  \
    }

    for (int base = 0; base < nt; base += 3) {
        GSTEP(base,     0, 2);
        GSTEP(base + 1, 1, 0);
        GSTEP(base + 2, 2, 1);
    }
#undef GSTEP
}

// ---------------------------------------------------------------------------
// Kernel 1: QKV = x @ qkv_w^T, scatter into q[bh][n][64] (pre-scaled by
// SCALE*log2e so softmax uses exp2), k[bh][n][64], vT[bh][64][n].
// grid (64, 18), block 256.
// ---------------------------------------------------------------------------
__global__ __launch_bounds__(256) void qkv_gemm(
    const ushort* __restrict__ X, const ushort* __restrict__ W,
    ushort* __restrict__ qb, ushort* __restrict__ kb, ushort* __restrict__ vb)
{
    __shared__ __align__(16) ushort As[3 * 128 * 32];
    __shared__ __align__(16) ushort Bs[3 * 128 * 32];
    f32x4 acc[4][4];
    const int br = blockIdx.x, bc = blockIdx.y;
    gemm128_mainloop(X, W, 768, br * 128, bc * 128, As, Bs, acc);

    const int t = threadIdx.x, l = t & 63, w = t >> 6;
    const int lr = l & 15, lg = l >> 4, wm = w >> 1, wn = w & 1;
    const int p = (bc * 128) / 768;
    const int mrow0 = br * 128 + wm * 64 + lg * 4;
    const int ecolB = bc * 128 + wn * 64 + lr;
    const float QSCALE = 0.125f * 1.44269504088896f;  // SCALE * log2(e)

#pragma unroll
    for (int n = 0; n < 4; n++) {
        const int e   = ecolB + n * 16;
        const int rem = e - p * 768;
        const int h   = rem >> 6;
        const int hd  = rem & 63;
#pragma unroll
        for (int m = 0; m < 4; m++) {
            const int mr = mrow0 + m * 16;
            const int b  = mr >> 10;
            const int nn = mr & 1023;
            const f32x4 v = acc[m][n];
            const int bh = b * 12 + h;
            if (p == 0) {
                ushort* dst = qb + (bh * 1024 + nn) * 64 + hd;
#pragma unroll
                for (int r = 0; r < 4; r++) dst[r * 64] = f2bf(v[r] * QSCALE);
            } else if (p == 1) {
                ushort* dst = kb + (bh * 1024 + nn) * 64 + hd;
#pragma unroll
                for (int r = 0; r < 4; r++) dst[r * 64] = f2bf(v[r]);
            } else {
                u16x4 pk;
                pk[0] = f2bf(v[0]); pk[1] = f2bf(v[1]);
                pk[2] = f2bf(v[2]); pk[3] = f2bf(v[3]);
                *(u16x4*)(vb + (bh * 64 + hd) * 1024 + nn) = pk;
            }
        }
    }
}

// ---------------------------------------------------------------------------
// Kernel 2: flash attention, 32x32 swapped-QK, KVBLK=32 (unchanged from R6).
// grid (96 bh, 8 qt); K/V staged in LDS (coalesced gload_lds, double-buffered,
// source-side XOR swizzle), block-shared; softmax fully in-register.
// ---------------------------------------------------------------------------
__global__ __launch_bounds__(256) void attn_kernel(
    const ushort* __restrict__ qb, const ushort* __restrict__ kb,
    const ushort* __restrict__ vb, ushort* __restrict__ ao)
{
    __shared__ __align__(16) ushort KV[2][4096];   // [buf][K 2048 | V 2048] = 16KB
    const int bh = blockIdx.x, qt = blockIdx.y;
    const int b = bh / 12, h = bh - b * 12;
    const int t = threadIdx.x, l = t & 63, w = t >> 6;
    const int lq = l & 31, hi = l >> 5;
    const int qr0 = qt * 128 + w * 32;

    // ---- staging source addresses (pre-swizzled) ----
    const int l3 = l >> 3, l7 = l & 7;
    const int ku = w * 8 + l3;                      // LDS row this lane fills
    const int pfv = l7 ^ l3;                        // swizzled 16B slot index
    const char* ksrc = (const char*)kb + (size_t)(bh * 1024 + ku) * 128
                     + ((l7 ^ l3) << 4);            // + kv0*128 per iter
    const char* vsrc = (const char*)vb + (size_t)(bh * 64 + ku + 32 * ((pfv >> 2) & 1)) * 2048
                     + ((pfv & 3) << 4);            // + kv0*2 per iter
    ushort* kdst = &KV[0][0]    + w * 512 + l * 8;  // uniform base + lane*16B
    ushort* vdst = &KV[0][2048] + w * 512 + l * 8;

    // ---- Q fragments (B-operand): col=q=lq, k=d-slice s*16 + hi*8 ----
    const ushort* qlane = qb + (bh * 1024 + qr0 + lq) * 64 + hi * 8;
    s16x8 qf[4];
#pragma unroll
    for (int s = 0; s < 4; s++) qf[s] = *(const s16x8*)(qlane + s * 16);

    float m = -__builtin_inff();
    float lsum = 0.f;
    f32x16 o0 = {}, o1 = {};

    // prologue: stage tile 0 into buf 0
    gload_lds16((const ushort*)ksrc, kdst);
    gload_lds16((const ushort*)vsrc, vdst);
    __syncthreads();

    const int fx = (lq & 7) << 4;                   // read-side swizzle
    for (int it = 0; it < 32; ++it) {
        const int cur = it & 1;
        // ---- prefetch next tile into the other buffer ----
        if (it < 31) {
            const int kvn = (it + 1) * 32;
            gload_lds16((const ushort*)(ksrc + kvn * 128), kdst + (cur ^ 1) * 4096);
            gload_lds16((const ushort*)(vsrc + kvn * 2),   vdst + (cur ^ 1) * 4096);
        }
        const char* Kb = (const char*)&KV[cur][0];
        const char* Vb = (const char*)&KV[cur][2048];

        // ---- K fragments (A-operand): row kv=lq, d-slice s*16+hi*8 ----
        s16x8 kf[4];
#pragma unroll
        for (int s = 0; s < 4; s++)
            kf[s] = *(const s16x8*)(Kb + lq * 128 + ((hi * 16 + s * 32) ^ fx));

        f32x16 sa = {};
        __builtin_amdgcn_s_setprio(1);
#pragma unroll
        for (int s = 0; s < 4; s++) sa = MFMA32(kf[s], qf[s], sa);
        __builtin_amdgcn_s_setprio(0);

        // ---- in-register online softmax (16 k/lane, pair lane has rest) ----
        float tm[8];
#pragma unroll
        for (int r = 0; r < 8; r++) tm[r] = fmaxf(sa[r], sa[r + 8]);
#pragma unroll
        for (int s = 4; s; s >>= 1)
#pragma unroll
            for (int r = 0; r < s; r++) tm[r] = fmaxf(tm[r], tm[r + s]);
        const float mx = pairmax(tm[0]);

        if (!__all(mx <= m + 8.f)) {          // defer-max (T13), log2 units
            const float mn = fmaxf(m, mx);
            const float fac = fast_exp2(m - mn);
            m = mn;
            lsum *= fac;
#pragma unroll
            for (int r = 0; r < 16; r++) { o0[r] *= fac; o1[r] *= fac; }
        }

        float p[16];
#pragma unroll
        for (int r = 0; r < 16; r++) p[r] = fast_exp2(sa[r] - m);
        float ts[8];
#pragma unroll
        for (int r = 0; r < 8; r++) ts[r] = p[r] + p[r + 8];
#pragma unroll
        for (int s = 4; s; s >>= 1)
#pragma unroll
            for (int r = 0; r < s; r++) ts[r] += ts[r + s];
        lsum += pairsum(ts[0]);

        // ---- pack P^T into PV B-fragments (cvt_pk + permlane32_swap) ----
        s16x8 pfr[2];
#pragma unroll
        for (int slot = 0; slot < 2; slot++) {
            const int r0 = slot * 8;
            unsigned a0 = cvtpk_bf16(p[r0 + 0], p[r0 + 1]);
            unsigned a1 = cvtpk_bf16(p[r0 + 4], p[r0 + 5]);
            plswap(a0, a1);
            unsigned b0 = cvtpk_bf16(p[r0 + 2], p[r0 + 3]);
            unsigned b1 = cvtpk_bf16(p[r0 + 6], p[r0 + 7]);
            plswap(b0, b1);
            const u32x4 u = {a0, b0, a1, b1};
            pfr[slot] = __builtin_bit_cast(s16x8, u);
        }

        // ---- V fragments + PV: O^T += V^T * P^T ----
        s16x8 vf[2][2];   // [half d0/d32][k-slot]
#pragma unroll
        for (int half = 0; half < 2; half++)
#pragma unroll
            for (int s = 0; s < 2; s++)
                vf[half][s] = *(const s16x8*)(Vb + lq * 128 + ((half * 64 + hi * 16 + s * 32) ^ fx));
        __builtin_amdgcn_s_setprio(1);
        o0 = MFMA32(vf[0][0], pfr[0], o0);
        o1 = MFMA32(vf[1][0], pfr[0], o1);
        o0 = MFMA32(vf[0][1], pfr[1], o0);
        o1 = MFMA32(vf[1][1], pfr[1], o1);
        __builtin_amdgcn_s_setprio(0);

        __syncthreads();   // drains prefetch (vmcnt) + all reads of cur buf
    }

    // ---- epilogue: out[b][q][h*64+d] = O^T[d][q] / lsum ----
    const float inv = 1.f / lsum;
    ushort* op = ao + (b * 1024 + qr0 + lq) * 768 + h * 64 + 4 * hi;
#pragma unroll
    for (int i = 0; i < 4; i++) {
        u16x4 pk0, pk1;
#pragma unroll
        for (int j = 0; j < 4; j++) {
            pk0[j] = f2bf(o0[4 * i + j] * inv);
            pk1[j] = f2bf(o1[4 * i + j] * inv);
        }
        *(u16x4*)(op + 8 * i)      = pk0;   // d = 8i+4hi + 0..3
        *(u16x4*)(op + 32 + 8 * i) = pk1;   // d = 32 + 8i+4hi + 0..3
    }
}

// ---------------------------------------------------------------------------
// Kernel 3: out = attn_out @ proj_w^T + proj_b (fp32 out). grid (64, 6).
// ---------------------------------------------------------------------------
__global__ __launch_bounds__(256) void proj_gemm(
    const ushort* __restrict__ A, const ushort* __restrict__ W,
    const float* __restrict__ bias, float* __restrict__ out)
{
    __shared__ __align__(16) ushort As[3 * 128 * 32];
    __shared__ __align__(16) ushort Bs[3 * 128 * 32];
    f32x4 acc[4][4];
    const int br = blockIdx.x, bc = blockIdx.y;
    gemm128_mainloop(A, W, 768, br * 128, bc * 128, As, Bs, acc);

    const int t = threadIdx.x, l = t & 63, w = t >> 6;
    const int lr = l & 15, lg = l >> 4, wm = w >> 1, wn = w & 1;
    const int mrow0 = br * 128 + wm * 64 + lg * 4;
    const int ecolB = bc * 128 + wn * 64 + lr;

#pragma unroll
    for (int n = 0; n < 4; n++) {
        const int e = ecolB + n * 16;
        const float bv = bias[e];
#pragma unroll
        for (int m = 0; m < 4; m++) {
            const int mr = mrow0 + m * 16;
#pragma unroll
            for (int r = 0; r < 4; r++)
                out[(mr + r) * 768 + e] = acc[m][n][r] + bv;
        }
    }
}

// ---------------------------------------------------------------------------
extern "C" void kernel_launch(void* const* d_in, const int* in_sizes, int n_in,
                              void* d_out, int out_size, void* d_ws, size_t ws_size,
                              hipStream_t stream)
{
    const float* x  = (const float*)d_in[0];   // [8,1024,768] f32
    const float* wq = (const float*)d_in[1];   // [2304,768]   f32
    const float* wp = (const float*)d_in[2];   // [768,768]    f32
    const float* pb = (const float*)d_in[3];   // [768]        f32
    float* out = (float*)d_out;                // [8,1024,768] f32

    const int NX = 8 * 1024 * 768;             // 6291456
    const int NQ = 2304 * 768;                 // 1769472
    const int NP = 768 * 768;                  // 589824
    const int SEG = 8 * 12 * 1024 * 64;        // 6291456

    ushort* xb  = (ushort*)d_ws;               // x bf16; reused as ao after qkv
    ushort* wqb = xb + NX;
    ushort* wpb = wqb + NQ;
    ushort* qb  = wpb + NP;                    // q  [bh][n][64]  (pre-scaled)
    ushort* kb  = qb + SEG;                    // k  [bh][n][64]
    ushort* vb  = kb + SEG;                    // vT [bh][64][n]
    ushort* ao  = xb;                          // attn out aliases xb (dead by then)

    cvt_f32_bf16<<<2048, 256, 0, stream>>>(x,  xb,  NX / 4);
    cvt_f32_bf16<<<1024, 256, 0, stream>>>(wq, wqb, NQ / 4);
    cvt_f32_bf16<<<576,  256, 0, stream>>>(wp, wpb, NP / 4);

    qkv_gemm  <<<dim3(64, 18), 256, 0, stream>>>(xb, wqb, qb, kb, vb);
    attn_kernel<<<dim3(96, 8), 256, 0, stream>>>(qb, kb, vb, ao);
    proj_gemm <<<dim3(64, 6),  256, 0, stream>>>(ao, wpb, pb, out);
}